// Round 15
// baseline (540.422 us; speedup 1.0000x reference)
//
#include <hip/hip_runtime.h>
#include <hip/hip_bf16.h>
#include <hip/hip_fp8.h>
#include <stdint.h>
#include <type_traits>

#define NIN  1024
#define NOUT 1024
#define NB   4096   // batch
#define NCVT 448    // cvt blocks in fused prep kernel

typedef float f32x4  __attribute__((ext_vector_type(4)));
typedef float f32x16 __attribute__((ext_vector_type(16)));
typedef __bf16 bf16x8 __attribute__((ext_vector_type(8)));
typedef int   i32x4 __attribute__((ext_vector_type(4)));
typedef int   i32x8 __attribute__((ext_vector_type(8)));

typedef const __attribute__((address_space(1))) unsigned int* gp1_t;
typedef __attribute__((address_space(3))) unsigned int* lp3_t;

__device__ __forceinline__ void gload16(const void* g, void* l) {
    __builtin_amdgcn_global_load_lds((gp1_t)g, (lp3_t)l, 16, 0, 0);
}

__device__ __forceinline__ unsigned short f2bf(float f) {
    __bf16 h = (__bf16)f;
    return __builtin_bit_cast(unsigned short, h);
}

// pack 4 floats -> 4 e4m3fn bytes
__device__ __forceinline__ unsigned int pk4_fp8(float a, float b, float c, float d) {
#if __has_builtin(__builtin_amdgcn_cvt_pk_fp8_f32)
    int p = __builtin_amdgcn_cvt_pk_fp8_f32(a, b, 0, false);
    p = __builtin_amdgcn_cvt_pk_fp8_f32(c, d, p, true);
    return (unsigned int)p;
#else
    __hip_fp8_e4m3 qa(a), qb(b), qc(c), qd(d);
    return (unsigned int)qa.__x | ((unsigned int)qb.__x << 8) |
           ((unsigned int)qc.__x << 16) | ((unsigned int)qd.__x << 24);
#endif
}

#define BAR   __builtin_amdgcn_s_barrier()
#define LGK0  do { asm volatile("s_waitcnt lgkmcnt(0)" ::: "memory"); __builtin_amdgcn_sched_barrier(0); } while (0)
#define VMW8  do { asm volatile("s_waitcnt vmcnt(8)"  ::: "memory"); __builtin_amdgcn_sched_barrier(0); } while (0)
#define VMW2  do { asm volatile("s_waitcnt vmcnt(2)"  ::: "memory"); __builtin_amdgcn_sched_barrier(0); } while (0)
#define VMW0  do { asm volatile("s_waitcnt vmcnt(0)"  ::: "memory"); __builtin_amdgcn_sched_barrier(0); } while (0)

// ---- prep: x -> bf16 AND fp8 in one pass ----
__global__ void cvt_x_both(const float* __restrict__ x, unsigned short* __restrict__ xb,
                           unsigned int* __restrict__ xf8) {
    int i = blockIdx.x * blockDim.x + threadIdx.x;
    f32x4 v = reinterpret_cast<const f32x4*>(x)[i];
    ushort4 o;
    o.x = f2bf(v.x); o.y = f2bf(v.y); o.z = f2bf(v.z); o.w = f2bf(v.w);
    reinterpret_cast<ushort4*>(xb)[i] = o;
    xf8[i] = pk4_fp8(v.x, v.y, v.z, v.w);
}

// ---- prep: f32 -> bf16 (for w_mu) ----
__global__ void cvt_x_kernel(const float* __restrict__ x, unsigned short* __restrict__ xb) {
    int i = blockIdx.x * blockDim.x + threadIdx.x;
    f32x4 v = reinterpret_cast<const f32x4*>(x)[i];
    ushort4 o;
    o.x = f2bf(v.x); o.y = f2bf(v.y); o.z = f2bf(v.z); o.w = f2bf(v.w);
    reinterpret_cast<ushort4*>(xb)[i] = o;
}

// =====================================================================
// FUSED prep: blocks [0,64): y0 = x.w_mu^T (r2-proven 256x256 8-phase
// bf16 GEMM, 64 tiles); blocks [64,64+NCVT): rf8 = fp8(exp(wls)*r1)
// grid-stride (NT r1 loads); blocks [64+NCVT,+16): bias. The gemm and
// conversion are independent -> they overlap across CUs instead of
// serializing as two launches. DO_Y0=false for later sample-chunks.
// =====================================================================
template <bool DO_Y0>
__launch_bounds__(512, 2)
__global__ void fused_prep(const unsigned short* __restrict__ xb,
                           const unsigned short* __restrict__ wb,
                           unsigned short* __restrict__ yb,
                           const float* __restrict__ wls,
                           const float* __restrict__ r1,
                           unsigned int* __restrict__ rf8,
                           const float* __restrict__ bmu,
                           const float* __restrict__ bls,
                           const float* __restrict__ r2,
                           float* __restrict__ bias,
                           int s0, int sc, int stot) {
    __shared__ __align__(16) char smem[131072];
    const int bid = blockIdx.x;

    if (!DO_Y0 || bid >= 64) {
        // ---------- cvt_r1 / bias region ----------
        const int cbid = DO_Y0 ? (bid - 64) : bid;
        if (cbid < NCVT) {
            const unsigned int U = (unsigned int)sc << 18;   // f4 units
            for (unsigned int u = cbid * 512u + threadIdx.x; u < U; u += NCVT * 512u) {
                unsigned int i4 = u & 262143u;
                unsigned int c  = u >> 18;
                f32x4 ls = reinterpret_cast<const f32x4*>(wls)[i4];
                const f32x4* rp = reinterpret_cast<const f32x4*>(r1 + ((size_t)(s0 + c) << 20));
                f32x4 r = __builtin_nontemporal_load(rp + i4);
                rf8[u] = pk4_fp8(__expf(ls.x) * r.x, __expf(ls.y) * r.y,
                                 __expf(ls.z) * r.z, __expf(ls.w) * r.w);
            }
        } else if (DO_Y0) {
            // bias for ALL samples, computed once in chunk 0
            const int total = stot * NOUT;
            for (int i = (cbid - NCVT) * 512 + threadIdx.x; i < total; i += 16 * 512) {
                int o = i & (NOUT - 1);
                bias[i] = bmu[o] + __expf(bls[o]) * r2[i];
            }
        }
        return;
    }

    // ---------- y0 GEMM region (r2-proven structure, nwg = 64) ----------
    const int tid = threadIdx.x;
    const int l   = tid & 63;
    const int w   = tid >> 6;
    const int wr  = w >> 2, wc = w & 3;

    const int b   = bid;
    const int g   = (b & 7) * 8 + (b >> 3);
    const int mi  = g & 15;
    const int ni  = g >> 4;
    const int m0  = mi * 256;
    const int n0  = ni * 256;

    const int srow = l >> 3;
    const int scol = ((l & 7) ^ srow) * 8;
    const size_t slane = (size_t)srow * NIN + scol;

    const int rowp  = (l & 15) * 128;
    const int colp0 = ((l >> 4) ^ (l & 7)) << 4;

    f32x4 acc[8][4] = {};
    bf16x8 aF[4][2], b0F[2][2], b1F[2][2];

    const unsigned short* xbase = xb + (size_t)m0 * NIN;
    const unsigned short* wbase = wb + (size_t)n0 * NIN;

    auto STAGE = [&](int buf, int kt, int q) {
        const int R = (q & 3) * 64 + w * 8;
        const unsigned short* src = ((q < 4) ? xbase : wbase)
                                    + (size_t)R * NIN + kt * 64 + slane;
        char* dst = smem + buf * 65536 + ((q >= 4) ? 32768 : 0) + R * 128;
        gload16(src, dst);
    };
    auto LDA = [&](int buf, int mh) {
        const char* base = smem + buf * 65536 + (wr * 128 + mh * 64) * 128 + rowp;
        #pragma unroll
        for (int mb = 0; mb < 4; ++mb) {
            aF[mb][0] = *(const bf16x8*)(base + mb * 2048 + colp0);
            aF[mb][1] = *(const bf16x8*)(base + mb * 2048 + (colp0 ^ 64));
        }
    };
    auto LDB = [&](bf16x8 (&bF)[2][2], int buf, int nh) {
        const char* base = smem + buf * 65536 + 32768 + (wc * 64 + nh * 32) * 128 + rowp;
        #pragma unroll
        for (int nb = 0; nb < 2; ++nb) {
            bF[nb][0] = *(const bf16x8*)(base + nb * 2048 + colp0);
            bF[nb][1] = *(const bf16x8*)(base + nb * 2048 + (colp0 ^ 64));
        }
    };
    auto MM = [&](auto MHc, auto NHc, bf16x8 (&bF)[2][2]) {
        constexpr int MH = decltype(MHc)::value;
        constexpr int NH = decltype(NHc)::value;
        __builtin_amdgcn_s_setprio(1);
        #pragma unroll
        for (int mb = 0; mb < 4; ++mb)
            #pragma unroll
            for (int nb = 0; nb < 2; ++nb)
                #pragma unroll
                for (int kk = 0; kk < 2; ++kk)
                    acc[MH * 4 + mb][NH * 2 + nb] = __builtin_amdgcn_mfma_f32_16x16x32_bf16(
                        aF[mb][kk], bF[nb][kk], acc[MH * 4 + mb][NH * 2 + nb], 0, 0, 0);
        __builtin_amdgcn_s_setprio(0);
    };

    auto C0 = std::integral_constant<int, 0>{};
    auto C1 = std::integral_constant<int, 1>{};

    auto ITER = [&](auto LASTc, int t1, int t2, int t3) {
        constexpr bool LAST = decltype(LASTc)::value;
        LDA(0, 0); LDB(b0F, 0, 0);
        STAGE(1, t1, 2); STAGE(1, t1, 3);
        BAR; LGK0; MM(C0, C0, b0F); BAR;
        LDB(b1F, 0, 1);
        STAGE(1, t1, 4); STAGE(1, t1, 5);
        BAR; LGK0; MM(C0, C1, b1F); BAR;
        LDA(0, 1);
        STAGE(1, t1, 6); STAGE(1, t1, 7);
        BAR; LGK0; MM(C1, C1, b1F); BAR;
        if constexpr (!LAST) { STAGE(0, t2, 0); STAGE(0, t2, 1); }
        BAR; MM(C1, C0, b0F);
        if constexpr (LAST) { VMW0; } else { VMW2; }
        BAR;
        LDA(1, 0); LDB(b0F, 1, 0);
        if constexpr (!LAST) { STAGE(0, t2, 2); STAGE(0, t2, 3); }
        BAR; LGK0; MM(C0, C0, b0F); BAR;
        LDB(b1F, 1, 1);
        if constexpr (!LAST) { STAGE(0, t2, 4); STAGE(0, t2, 5); }
        BAR; LGK0; MM(C0, C1, b1F); BAR;
        LDA(1, 1);
        if constexpr (!LAST) { STAGE(0, t2, 6); STAGE(0, t2, 7); }
        BAR; LGK0; MM(C1, C1, b1F); BAR;
        if constexpr (!LAST) {
            STAGE(1, t3, 0); STAGE(1, t3, 1);
            BAR; MM(C1, C0, b0F); VMW2; BAR;
        } else {
            MM(C1, C0, b0F);
        }
    };

    #pragma unroll
    for (int q = 0; q < 8; ++q) STAGE(0, 0, q);
    STAGE(1, 1, 0); STAGE(1, 1, 1);
    VMW2; BAR;

    #pragma unroll 1
    for (int i = 0; i < 7; ++i)
        ITER(std::false_type{}, 2 * i + 1, 2 * i + 2, 2 * i + 3);
    ITER(std::true_type{}, 15, 16, 17);

    const int oc = n0 + wc * 64 + (l & 15);
    #pragma unroll
    for (int mb = 0; mb < 8; ++mb) {
        #pragma unroll
        for (int i2 = 0; i2 < 4; ++i2) {
            int row = m0 + wr * 128 + mb * 16 + (l >> 4) * 4 + i2;
            unsigned short* rp = yb + (size_t)row * NOUT + oc;
            #pragma unroll
            for (int nb = 0; nb < 4; ++nb)
                rp[nb * 16] = f2bf(acc[mb][nb][i2]);
        }
    }
}

// =====================================================================
// MX-fp8 256x256 GEMM (r14 = best configuration, byte-identical):
//  - 32x32x64 mfma_scale, BK=128 bytes, 2x64KB double-buffer
//  - burst deep-slack staging, vmcnt(8) gates (4 phases of slack)
//  - ni-fastest grid with XCD chunking (A panel + y0 slice L2-resident)
//  - epilogue: LDS transpose + y0(bf16) + bias + NT float4 stores
// =====================================================================
__launch_bounds__(512, 2)
__global__ void gemm256mx(const unsigned char* __restrict__ xf8,
                          const unsigned char* __restrict__ rf8,
                          const unsigned short* __restrict__ y0b,
                          const float* __restrict__ bias,
                          float* __restrict__ out, int s0, int nwg) {
    __shared__ __align__(16) char smem[131072];
    const int tid = threadIdx.x;
    const int l   = tid & 63;
    const int w   = tid >> 6;
    const int wr  = w >> 2, wc = w & 3;   // 2M x 4N waves, wave tile 128x64

    const int b   = blockIdx.x;
    const int q8  = nwg >> 3;
    const int g   = (b & 7) * q8 + (b >> 3);
    const int nni = nwg >> 4;             // 4*sc N-indices
    const int mi  = g / nni;              // SLOW: A-panel + y0 slice stay in L2
    const int ni  = g - mi * nni;         // FAST: B streams, re-read via L3
    const int m0  = mi * 256;
    const int n0  = ni * 256;

    // staging lane geometry (fp8: rows are NIN bytes global, 128 B LDS)
    const int srow  = l >> 3;
    const int scolb = ((l & 7) ^ srow) * 16;
    const size_t slane = (size_t)srow * NIN + scolb;

    // frag-read geometry (32x32x64): row = l&31, read-key l&7
    const int arow = l & 31;
    const int swz  = l & 7;
    const int kgrp = (l >> 5) * 2;

    f32x16 acc[4][2] = {};
    i32x8 aF[2][2], b0F[2], b1F[2];

    const unsigned char* xbase = xf8 + (size_t)m0 * NIN;
    const unsigned char* rbase = rf8 + (size_t)n0 * NIN;

    auto STAGE = [&](int buf, int kt, int q) {
        const int R = (q & 3) * 64 + w * 8;
        const unsigned char* src = ((q < 4) ? xbase : rbase)
                                   + (size_t)R * NIN + kt * 128 + slane;
        char* dst = smem + buf * 65536 + ((q >= 4) ? 32768 : 0) + R * 128;
        gload16(src, dst);
    };
    auto STAGE8 = [&](int buf, int kt) {
        #pragma unroll
        for (int q = 0; q < 8; ++q) STAGE(buf, kt, q);
    };

    auto LDA = [&](int buf, int mh) {
        const char* base = smem + buf * 65536 + (wr * 128 + mh * 64 + arow) * 128;
        #pragma unroll
        for (int mb = 0; mb < 2; ++mb) {
            const char* rb = base + mb * 4096;
            #pragma unroll
            for (int ks = 0; ks < 2; ++ks) {
                int c = ks * 4 + kgrp;
                i32x4 lo = *(const i32x4*)(rb + ((c ^ swz) * 16));
                i32x4 hi = *(const i32x4*)(rb + (((c + 1) ^ swz) * 16));
                aF[mb][ks] = __builtin_shufflevector(lo, hi, 0, 1, 2, 3, 4, 5, 6, 7);
            }
        }
    };
    auto LDB = [&](i32x8 (&bF)[2], int buf, int nh) {
        const char* base = smem + buf * 65536 + 32768 + (wc * 64 + nh * 32 + arow) * 128;
        #pragma unroll
        for (int ks = 0; ks < 2; ++ks) {
            int c = ks * 4 + kgrp;
            i32x4 lo = *(const i32x4*)(base + ((c ^ swz) * 16));
            i32x4 hi = *(const i32x4*)(base + (((c + 1) ^ swz) * 16));
            bF[ks] = __builtin_shufflevector(lo, hi, 0, 1, 2, 3, 4, 5, 6, 7);
        }
    };

    auto MM = [&](auto MHc, auto NHc, i32x8 (&bF)[2]) {
        constexpr int MH = decltype(MHc)::value;
        constexpr int NH = decltype(NHc)::value;
        __builtin_amdgcn_s_setprio(1);
        #pragma unroll
        for (int mb = 0; mb < 2; ++mb)
            #pragma unroll
            for (int ks = 0; ks < 2; ++ks)
                acc[MH * 2 + mb][NH] = __builtin_amdgcn_mfma_scale_f32_32x32x64_f8f6f4(
                    aF[mb][ks], bF[ks], acc[MH * 2 + mb][NH],
                    0, 0, 0, 127, 0, 127);
        __builtin_amdgcn_s_setprio(0);
    };

    auto C0 = std::integral_constant<int, 0>{};
    auto C1 = std::integral_constant<int, 1>{};

    auto ITER = [&](auto LASTc, int t2, int t3) {
        constexpr bool LAST = decltype(LASTc)::value;
        LDA(0, 0); LDB(b0F, 0, 0);
        BAR; LGK0; MM(C0, C0, b0F); BAR;
        LDB(b1F, 0, 1);
        BAR; LGK0; MM(C0, C1, b1F); BAR;
        LDA(0, 1);
        BAR; LGK0; MM(C1, C1, b1F); BAR;   // all buf0 reads done
        if constexpr (!LAST) STAGE8(0, t2);
        BAR; MM(C1, C0, b0F);
        if constexpr (LAST) { VMW0; } else { VMW8; }
        BAR;
        LDA(1, 0); LDB(b0F, 1, 0);
        BAR; LGK0; MM(C0, C0, b0F); BAR;
        LDB(b1F, 1, 1);
        BAR; LGK0; MM(C0, C1, b1F); BAR;
        LDA(1, 1);
        BAR; LGK0; MM(C1, C1, b1F); BAR;   // all buf1 reads done
        if constexpr (!LAST) {
            STAGE8(1, t3);
            BAR; MM(C1, C0, b0F); VMW8; BAR;
        } else {
            MM(C1, C0, b0F);
        }
    };

    STAGE8(0, 0);
    STAGE8(1, 1);
    VMW8; BAR;

    #pragma unroll 1
    for (int i = 0; i < 3; ++i)
        ITER(std::false_type{}, 2 * i + 2, 2 * i + 3);
    ITER(std::true_type{}, 8, 9);

    // ---- epilogue: LDS transpose + y0(bf16) + bias + NT f4 stores ----
    // C/D map (verified r7): col = l&31, row = (reg&3) + 8*(reg>>2) + 4*(l>>5)
    const int s   = s0 + (n0 >> 10);
    const int n0c = n0 & 1023;
    float* outp = out + (size_t)s * NB * NOUT;
    float* lds_f = (float*)smem;     // [64][256] f32 chunk staging (64 KB)
    const f32x4 bvv = *(const f32x4*)(bias + (size_t)s * NOUT + n0c + l * 4);

    #pragma unroll
    for (int c = 0; c < 4; ++c) {    // chunk = rows [c*64, c*64+64) of the tile
        if (wr == (c >> 1)) {
            #pragma unroll
            for (int mbh = 0; mbh < 2; ++mbh) {
                const int mb = (c & 1) * 2 + mbh;
                #pragma unroll
                for (int nb = 0; nb < 2; ++nb) {
                    const int col = wc * 64 + nb * 32 + (l & 31);
                    #pragma unroll
                    for (int r = 0; r < 16; ++r) {
                        int rl = mbh * 32 + 4 * (l >> 5) + (r & 3) + 8 * (r >> 2);
                        lds_f[rl * 256 + col] = acc[mb][nb][r];
                    }
                }
            }
        }
        LGK0; BAR;
        #pragma unroll
        for (int k = 0; k < 8; ++k) {
            const int rl  = k * 8 + w;
            const int row = m0 + c * 64 + rl;
            f32x4 v  = *(const f32x4*)(lds_f + (rl * 64 + l) * 4);
            ushort4 yu = *(const ushort4*)(y0b + (size_t)row * NOUT + n0c + l * 4);
            f32x4 yv;
            yv.x = __builtin_bit_cast(float, (unsigned int)yu.x << 16);
            yv.y = __builtin_bit_cast(float, (unsigned int)yu.y << 16);
            yv.z = __builtin_bit_cast(float, (unsigned int)yu.z << 16);
            yv.w = __builtin_bit_cast(float, (unsigned int)yu.w << 16);
            f32x4 o  = v + yv + bvv;
            __builtin_nontemporal_store(o, (f32x4*)(outp + (size_t)row * NOUT + n0c + l * 4));
        }
        BAR;
    }
}

// ---- zero-scratch correctness fallback (only if ws_size is tiny) ----
__global__ void fused_fallback(const float* __restrict__ x, const float* __restrict__ wmu,
                               const float* __restrict__ wls, const float* __restrict__ r1,
                               const float* __restrict__ bmu, const float* __restrict__ bls,
                               const float* __restrict__ r2, float* __restrict__ out) {
    __shared__ float Xs[16][64];
    __shared__ float Ws[16][64];
    int b0 = blockIdx.x * 16, o0 = blockIdx.y * 16, s = blockIdx.z;
    int tb = threadIdx.x >> 4, to = threadIdx.x & 15;
    float acc = 0.f;
    for (int k0 = 0; k0 < NIN; k0 += 64) {
        __syncthreads();
        #pragma unroll
        for (int j = 0; j < 4; ++j) {
            int e = j * 256 + threadIdx.x;
            int r = e >> 6, cc = e & 63;
            Xs[r][cc] = x[(size_t)(b0 + r) * NIN + k0 + cc];
            size_t wi = (size_t)(o0 + r) * NIN + k0 + cc;
            Ws[r][cc] = wmu[wi] + __expf(wls[wi]) * r1[(size_t)s * NIN * NOUT + wi];
        }
        __syncthreads();
        for (int k = 0; k < 64; ++k) acc += Xs[tb][k] * Ws[to][k];
    }
    int o = o0 + to;
    out[((size_t)s * NB + b0 + tb) * NOUT + o] = acc + bmu[o] + __expf(bls[o]) * r2[s * NOUT + o];
}

extern "C" void kernel_launch(void* const* d_in, const int* in_sizes, int n_in,
                              void* d_out, int out_size, void* d_ws, size_t ws_size,
                              hipStream_t stream) {
    const float* x   = (const float*)d_in[0];
    const float* wmu = (const float*)d_in[1];
    const float* wls = (const float*)d_in[2];
    const float* bmu = (const float*)d_in[3];
    const float* bls = (const float*)d_in[4];
    const float* r1  = (const float*)d_in[5];
    const float* r2  = (const float*)d_in[6];
    const int S = in_sizes[6] / NOUT;
    float* out = (float*)d_out;

    const size_t xb_b   = (size_t)NB * NIN * 2;       // 8 MB  bf16 x
    const size_t xf8_b  = (size_t)NB * NIN;           // 4 MB  fp8 x
    const size_t wmub_b = (size_t)NOUT * NIN * 2;     // 2 MB  bf16 w_mu
    const size_t y0_b   = (size_t)NB * NOUT * 2;      // 8 MB  bf16 y0
    const size_t bias_b = (size_t)S * NOUT * 4;
    const size_t per_s  = (size_t)NOUT * NIN;         // 1 MB fp8 per sample
    const size_t base_b = xb_b + xf8_b + wmub_b + y0_b + bias_b;

    if (ws_size < base_b + per_s) {
        dim3 gg(NB / 16, NOUT / 16, S);
        fused_fallback<<<gg, 256, 0, stream>>>(x, wmu, wls, r1, bmu, bls, r2, out);
        return;
    }

    char* ws = (char*)d_ws;
    unsigned short* xb   = (unsigned short*)ws;
    unsigned char*  xf8  = (unsigned char*)(ws + xb_b);
    unsigned short* wmub = (unsigned short*)(ws + xb_b + xf8_b);
    unsigned short* y0b  = (unsigned short*)(ws + xb_b + xf8_b + wmub_b);
    float*          bias = (float*)(ws + xb_b + xf8_b + wmub_b + y0_b);
    unsigned char*  rf8  = (unsigned char*)(ws + base_b);

    int SC = (int)((ws_size - base_b) / per_s);
    if (SC > S) SC = S;

    cvt_x_both<<<NB * NIN / 1024, 256, 0, stream>>>(x, xb, (unsigned int*)xf8);
    cvt_x_kernel<<<NOUT * NIN / 1024, 256, 0, stream>>>(wmu, wmub);

    bool first = true;
    for (int s0 = 0; s0 < S; s0 += SC) {
        int sc = (S - s0 < SC) ? (S - s0) : SC;
        if (first) {
            // y0 gemm (64 blocks) + r1 conversion (NCVT blocks) + bias (16)
            fused_prep<true><<<64 + NCVT + 16, 512, 0, stream>>>(
                xb, wmub, y0b, wls, r1, (unsigned int*)rf8, bmu, bls, r2, bias, s0, sc, S);
            first = false;
        } else {
            fused_prep<false><<<NCVT, 512, 0, stream>>>(
                xb, wmub, y0b, wls, r1, (unsigned int*)rf8, bmu, bls, r2, bias, s0, sc, S);
        }
        int nwg = 64 * sc;   // 16 mi x 4*sc ni, always % 8 == 0
        gemm256mx<<<nwg, 512, 0, stream>>>(xf8, rf8, y0b, bias, out, s0, nwg);
    }
}

// Round 16
// 524.002 us; speedup vs baseline: 1.0313x; 1.0313x over previous
//
#include <hip/hip_runtime.h>
#include <hip/hip_bf16.h>
#include <hip/hip_fp8.h>
#include <stdint.h>
#include <type_traits>

#define NIN  1024
#define NOUT 1024
#define NB   4096   // batch

typedef float f32x4  __attribute__((ext_vector_type(4)));
typedef float f32x16 __attribute__((ext_vector_type(16)));
typedef __bf16 bf16x8 __attribute__((ext_vector_type(8)));
typedef int   i32x4 __attribute__((ext_vector_type(4)));
typedef int   i32x8 __attribute__((ext_vector_type(8)));

typedef const __attribute__((address_space(1))) unsigned int* gp1_t;
typedef __attribute__((address_space(3))) unsigned int* lp3_t;

__device__ __forceinline__ void gload16(const void* g, void* l) {
    __builtin_amdgcn_global_load_lds((gp1_t)g, (lp3_t)l, 16, 0, 0);
}

__device__ __forceinline__ unsigned short f2bf(float f) {
    __bf16 h = (__bf16)f;
    return __builtin_bit_cast(unsigned short, h);
}

// pack 4 floats -> 4 e4m3fn bytes
__device__ __forceinline__ unsigned int pk4_fp8(float a, float b, float c, float d) {
#if __has_builtin(__builtin_amdgcn_cvt_pk_fp8_f32)
    int p = __builtin_amdgcn_cvt_pk_fp8_f32(a, b, 0, false);
    p = __builtin_amdgcn_cvt_pk_fp8_f32(c, d, p, true);
    return (unsigned int)p;
#else
    __hip_fp8_e4m3 qa(a), qb(b), qc(c), qd(d);
    return (unsigned int)qa.__x | ((unsigned int)qb.__x << 8) |
           ((unsigned int)qc.__x << 16) | ((unsigned int)qd.__x << 24);
#endif
}

#define BAR   __builtin_amdgcn_s_barrier()
#define LGK0  do { asm volatile("s_waitcnt lgkmcnt(0)" ::: "memory"); __builtin_amdgcn_sched_barrier(0); } while (0)
#define VMW8  do { asm volatile("s_waitcnt vmcnt(8)"  ::: "memory"); __builtin_amdgcn_sched_barrier(0); } while (0)
#define VMW2  do { asm volatile("s_waitcnt vmcnt(2)"  ::: "memory"); __builtin_amdgcn_sched_barrier(0); } while (0)
#define VMW0  do { asm volatile("s_waitcnt vmcnt(0)"  ::: "memory"); __builtin_amdgcn_sched_barrier(0); } while (0)

// ---- prep: x -> bf16 AND fp8 in one pass ----
__global__ void cvt_x_both(const float* __restrict__ x, unsigned short* __restrict__ xb,
                           unsigned int* __restrict__ xf8) {
    int i = blockIdx.x * blockDim.x + threadIdx.x;
    f32x4 v = reinterpret_cast<const f32x4*>(x)[i];
    ushort4 o;
    o.x = f2bf(v.x); o.y = f2bf(v.y); o.z = f2bf(v.z); o.w = f2bf(v.w);
    reinterpret_cast<ushort4*>(xb)[i] = o;
    xf8[i] = pk4_fp8(v.x, v.y, v.z, v.w);
}

// ---- prep: f32 -> bf16 (for w_mu) ----
__global__ void cvt_x_kernel(const float* __restrict__ x, unsigned short* __restrict__ xb) {
    int i = blockIdx.x * blockDim.x + threadIdx.x;
    f32x4 v = reinterpret_cast<const f32x4*>(x)[i];
    ushort4 o;
    o.x = f2bf(v.x); o.y = f2bf(v.y); o.z = f2bf(v.z); o.w = f2bf(v.w);
    reinterpret_cast<ushort4*>(xb)[i] = o;
}

// ---- prep: rf8[c,o,i] = fp8( exp(wls[o,i]) * r1[s0+c,o,i] ), NT r1 loads ----
__global__ void cvt_r1_fp8(const float* __restrict__ wls, const float* __restrict__ r1,
                           unsigned int* __restrict__ rf8, int s0) {
    int idx = blockIdx.x * blockDim.x + threadIdx.x;
    int i4 = idx & 262143;
    int c  = idx >> 18;
    f32x4 ls = reinterpret_cast<const f32x4*>(wls)[i4];
    const f32x4* rp = reinterpret_cast<const f32x4*>(r1 + ((size_t)(s0 + c) << 20));
    f32x4 r = __builtin_nontemporal_load(rp + i4);
    rf8[idx] = pk4_fp8(__expf(ls.x) * r.x, __expf(ls.y) * r.y,
                       __expf(ls.z) * r.z, __expf(ls.w) * r.w);
}

// ---- prep: bias[s,o] = b_mu[o] + exp(b_ls[o]) * r2[s,o] ----
__global__ void bias_kernel(const float* __restrict__ bmu, const float* __restrict__ bls,
                            const float* __restrict__ r2, float* __restrict__ bias, int total) {
    int i = blockIdx.x * blockDim.x + threadIdx.x;
    if (i < total) {
        int o = i & (NOUT - 1);
        bias[i] = bmu[o] + __expf(bls[o]) * r2[i];
    }
}

// =====================================================================
// bf16 256x256 8-phase GEMM (r2-proven schedule): y0 = x.w_mu^T, bf16 out
// =====================================================================
__launch_bounds__(512, 2)
__global__ void gemm256(const unsigned short* __restrict__ xb,
                        const unsigned short* __restrict__ wb,
                        unsigned short* __restrict__ yb, int nwg) {
    __shared__ __align__(16) char smem[131072];
    const int tid = threadIdx.x;
    const int l   = tid & 63;
    const int w   = tid >> 6;
    const int wr  = w >> 2, wc = w & 3;

    const int b   = blockIdx.x;
    const int q8  = nwg >> 3;
    const int g   = (b & 7) * q8 + (b >> 3);
    const int mi  = g & 15;
    const int ni  = g >> 4;
    const int m0  = mi * 256;
    const int n0  = ni * 256;

    const int srow = l >> 3;
    const int scol = ((l & 7) ^ srow) * 8;
    const size_t slane = (size_t)srow * NIN + scol;

    const int rowp  = (l & 15) * 128;
    const int colp0 = ((l >> 4) ^ (l & 7)) << 4;

    f32x4 acc[8][4] = {};
    bf16x8 aF[4][2], b0F[2][2], b1F[2][2];

    const unsigned short* xbase = xb + (size_t)m0 * NIN;
    const unsigned short* wbase = wb + (size_t)n0 * NIN;

    auto STAGE = [&](int buf, int kt, int q) {
        const int R = (q & 3) * 64 + w * 8;
        const unsigned short* src = ((q < 4) ? xbase : wbase)
                                    + (size_t)R * NIN + kt * 64 + slane;
        char* dst = smem + buf * 65536 + ((q >= 4) ? 32768 : 0) + R * 128;
        gload16(src, dst);
    };
    auto LDA = [&](int buf, int mh) {
        const char* base = smem + buf * 65536 + (wr * 128 + mh * 64) * 128 + rowp;
        #pragma unroll
        for (int mb = 0; mb < 4; ++mb) {
            aF[mb][0] = *(const bf16x8*)(base + mb * 2048 + colp0);
            aF[mb][1] = *(const bf16x8*)(base + mb * 2048 + (colp0 ^ 64));
        }
    };
    auto LDB = [&](bf16x8 (&bF)[2][2], int buf, int nh) {
        const char* base = smem + buf * 65536 + 32768 + (wc * 64 + nh * 32) * 128 + rowp;
        #pragma unroll
        for (int nb = 0; nb < 2; ++nb) {
            bF[nb][0] = *(const bf16x8*)(base + nb * 2048 + colp0);
            bF[nb][1] = *(const bf16x8*)(base + nb * 2048 + (colp0 ^ 64));
        }
    };
    auto MM = [&](auto MHc, auto NHc, bf16x8 (&bF)[2][2]) {
        constexpr int MH = decltype(MHc)::value;
        constexpr int NH = decltype(NHc)::value;
        __builtin_amdgcn_s_setprio(1);
        #pragma unroll
        for (int mb = 0; mb < 4; ++mb)
            #pragma unroll
            for (int nb = 0; nb < 2; ++nb)
                #pragma unroll
                for (int kk = 0; kk < 2; ++kk)
                    acc[MH * 4 + mb][NH * 2 + nb] = __builtin_amdgcn_mfma_f32_16x16x32_bf16(
                        aF[mb][kk], bF[nb][kk], acc[MH * 4 + mb][NH * 2 + nb], 0, 0, 0);
        __builtin_amdgcn_s_setprio(0);
    };

    auto C0 = std::integral_constant<int, 0>{};
    auto C1 = std::integral_constant<int, 1>{};

    auto ITER = [&](auto LASTc, int t1, int t2, int t3) {
        constexpr bool LAST = decltype(LASTc)::value;
        LDA(0, 0); LDB(b0F, 0, 0);
        STAGE(1, t1, 2); STAGE(1, t1, 3);
        BAR; LGK0; MM(C0, C0, b0F); BAR;
        LDB(b1F, 0, 1);
        STAGE(1, t1, 4); STAGE(1, t1, 5);
        BAR; LGK0; MM(C0, C1, b1F); BAR;
        LDA(0, 1);
        STAGE(1, t1, 6); STAGE(1, t1, 7);
        BAR; LGK0; MM(C1, C1, b1F); BAR;
        if constexpr (!LAST) { STAGE(0, t2, 0); STAGE(0, t2, 1); }
        BAR; MM(C1, C0, b0F);
        if constexpr (LAST) { VMW0; } else { VMW2; }
        BAR;
        LDA(1, 0); LDB(b0F, 1, 0);
        if constexpr (!LAST) { STAGE(0, t2, 2); STAGE(0, t2, 3); }
        BAR; LGK0; MM(C0, C0, b0F); BAR;
        LDB(b1F, 1, 1);
        if constexpr (!LAST) { STAGE(0, t2, 4); STAGE(0, t2, 5); }
        BAR; LGK0; MM(C0, C1, b1F); BAR;
        LDA(1, 1);
        if constexpr (!LAST) { STAGE(0, t2, 6); STAGE(0, t2, 7); }
        BAR; LGK0; MM(C1, C1, b1F); BAR;
        if constexpr (!LAST) {
            STAGE(1, t3, 0); STAGE(1, t3, 1);
            BAR; MM(C1, C0, b0F); VMW2; BAR;
        } else {
            MM(C1, C0, b0F);
        }
    };

    #pragma unroll
    for (int q = 0; q < 8; ++q) STAGE(0, 0, q);
    STAGE(1, 1, 0); STAGE(1, 1, 1);
    VMW2; BAR;

    #pragma unroll 1
    for (int i = 0; i < 7; ++i)
        ITER(std::false_type{}, 2 * i + 1, 2 * i + 2, 2 * i + 3);
    ITER(std::true_type{}, 15, 16, 17);

    const int oc = n0 + wc * 64 + (l & 15);
    #pragma unroll
    for (int mb = 0; mb < 8; ++mb) {
        #pragma unroll
        for (int i2 = 0; i2 < 4; ++i2) {
            int row = m0 + wr * 128 + mb * 16 + (l >> 4) * 4 + i2;
            unsigned short* rp = yb + (size_t)row * NOUT + oc;
            #pragma unroll
            for (int nb = 0; nb < 4; ++nb)
                rp[nb * 16] = f2bf(acc[mb][nb][i2]);
        }
    }
}

// =====================================================================
// MX-fp8 256x256 GEMM (r14 best configuration, byte-identical):
//  - 32x32x64 mfma_scale, BK=128 bytes, 2x64KB double-buffer
//  - burst deep-slack staging, vmcnt(8) gates (4 phases of slack)
//  - ni-fastest grid with XCD chunking (A panel + y0 slice L2-resident)
//  - epilogue: LDS transpose + y0(bf16) + bias + NT float4 stores
// =====================================================================
__launch_bounds__(512, 2)
__global__ void gemm256mx(const unsigned char* __restrict__ xf8,
                          const unsigned char* __restrict__ rf8,
                          const unsigned short* __restrict__ y0b,
                          const float* __restrict__ bias,
                          float* __restrict__ out, int s0, int nwg) {
    __shared__ __align__(16) char smem[131072];
    const int tid = threadIdx.x;
    const int l   = tid & 63;
    const int w   = tid >> 6;
    const int wr  = w >> 2, wc = w & 3;   // 2M x 4N waves, wave tile 128x64

    const int b   = blockIdx.x;
    const int q8  = nwg >> 3;
    const int g   = (b & 7) * q8 + (b >> 3);
    const int nni = nwg >> 4;             // 4*sc N-indices
    const int mi  = g / nni;              // SLOW: A-panel + y0 slice stay in L2
    const int ni  = g - mi * nni;         // FAST: B streams, re-read via L3
    const int m0  = mi * 256;
    const int n0  = ni * 256;

    // staging lane geometry (fp8: rows are NIN bytes global, 128 B LDS)
    const int srow  = l >> 3;
    const int scolb = ((l & 7) ^ srow) * 16;
    const size_t slane = (size_t)srow * NIN + scolb;

    // frag-read geometry (32x32x64): row = l&31, read-key l&7
    const int arow = l & 31;
    const int swz  = l & 7;
    const int kgrp = (l >> 5) * 2;

    f32x16 acc[4][2] = {};
    i32x8 aF[2][2], b0F[2], b1F[2];

    const unsigned char* xbase = xf8 + (size_t)m0 * NIN;
    const unsigned char* rbase = rf8 + (size_t)n0 * NIN;

    auto STAGE = [&](int buf, int kt, int q) {
        const int R = (q & 3) * 64 + w * 8;
        const unsigned char* src = ((q < 4) ? xbase : rbase)
                                   + (size_t)R * NIN + kt * 128 + slane;
        char* dst = smem + buf * 65536 + ((q >= 4) ? 32768 : 0) + R * 128;
        gload16(src, dst);
    };
    auto STAGE8 = [&](int buf, int kt) {
        #pragma unroll
        for (int q = 0; q < 8; ++q) STAGE(buf, kt, q);
    };

    auto LDA = [&](int buf, int mh) {
        const char* base = smem + buf * 65536 + (wr * 128 + mh * 64 + arow) * 128;
        #pragma unroll
        for (int mb = 0; mb < 2; ++mb) {
            const char* rb = base + mb * 4096;
            #pragma unroll
            for (int ks = 0; ks < 2; ++ks) {
                int c = ks * 4 + kgrp;
                i32x4 lo = *(const i32x4*)(rb + ((c ^ swz) * 16));
                i32x4 hi = *(const i32x4*)(rb + (((c + 1) ^ swz) * 16));
                aF[mb][ks] = __builtin_shufflevector(lo, hi, 0, 1, 2, 3, 4, 5, 6, 7);
            }
        }
    };
    auto LDB = [&](i32x8 (&bF)[2], int buf, int nh) {
        const char* base = smem + buf * 65536 + 32768 + (wc * 64 + nh * 32 + arow) * 128;
        #pragma unroll
        for (int ks = 0; ks < 2; ++ks) {
            int c = ks * 4 + kgrp;
            i32x4 lo = *(const i32x4*)(base + ((c ^ swz) * 16));
            i32x4 hi = *(const i32x4*)(base + (((c + 1) ^ swz) * 16));
            bF[ks] = __builtin_shufflevector(lo, hi, 0, 1, 2, 3, 4, 5, 6, 7);
        }
    };

    auto MM = [&](auto MHc, auto NHc, i32x8 (&bF)[2]) {
        constexpr int MH = decltype(MHc)::value;
        constexpr int NH = decltype(NHc)::value;
        __builtin_amdgcn_s_setprio(1);
        #pragma unroll
        for (int mb = 0; mb < 2; ++mb)
            #pragma unroll
            for (int ks = 0; ks < 2; ++ks)
                acc[MH * 2 + mb][NH] = __builtin_amdgcn_mfma_scale_f32_32x32x64_f8f6f4(
                    aF[mb][ks], bF[ks], acc[MH * 2 + mb][NH],
                    0, 0, 0, 127, 0, 127);
        __builtin_amdgcn_s_setprio(0);
    };

    auto C0 = std::integral_constant<int, 0>{};
    auto C1 = std::integral_constant<int, 1>{};

    auto ITER = [&](auto LASTc, int t2, int t3) {
        constexpr bool LAST = decltype(LASTc)::value;
        LDA(0, 0); LDB(b0F, 0, 0);
        BAR; LGK0; MM(C0, C0, b0F); BAR;
        LDB(b1F, 0, 1);
        BAR; LGK0; MM(C0, C1, b1F); BAR;
        LDA(0, 1);
        BAR; LGK0; MM(C1, C1, b1F); BAR;   // all buf0 reads done
        if constexpr (!LAST) STAGE8(0, t2);
        BAR; MM(C1, C0, b0F);
        if constexpr (LAST) { VMW0; } else { VMW8; }
        BAR;
        LDA(1, 0); LDB(b0F, 1, 0);
        BAR; LGK0; MM(C0, C0, b0F); BAR;
        LDB(b1F, 1, 1);
        BAR; LGK0; MM(C0, C1, b1F); BAR;
        LDA(1, 1);
        BAR; LGK0; MM(C1, C1, b1F); BAR;   // all buf1 reads done
        if constexpr (!LAST) {
            STAGE8(1, t3);
            BAR; MM(C1, C0, b0F); VMW8; BAR;
        } else {
            MM(C1, C0, b0F);
        }
    };

    STAGE8(0, 0);
    STAGE8(1, 1);
    VMW8; BAR;

    #pragma unroll 1
    for (int i = 0; i < 3; ++i)
        ITER(std::false_type{}, 2 * i + 2, 2 * i + 3);
    ITER(std::true_type{}, 8, 9);

    // ---- epilogue: LDS transpose + y0(bf16) + bias + NT f4 stores ----
    // C/D map (verified r7): col = l&31, row = (reg&3) + 8*(reg>>2) + 4*(l>>5)
    const int s   = s0 + (n0 >> 10);
    const int n0c = n0 & 1023;
    float* outp = out + (size_t)s * NB * NOUT;
    float* lds_f = (float*)smem;     // [64][256] f32 chunk staging (64 KB)
    const f32x4 bvv = *(const f32x4*)(bias + (size_t)s * NOUT + n0c + l * 4);

    #pragma unroll
    for (int c = 0; c < 4; ++c) {    // chunk = rows [c*64, c*64+64) of the tile
        if (wr == (c >> 1)) {
            #pragma unroll
            for (int mbh = 0; mbh < 2; ++mbh) {
                const int mb = (c & 1) * 2 + mbh;
                #pragma unroll
                for (int nb = 0; nb < 2; ++nb) {
                    const int col = wc * 64 + nb * 32 + (l & 31);
                    #pragma unroll
                    for (int r = 0; r < 16; ++r) {
                        int rl = mbh * 32 + 4 * (l >> 5) + (r & 3) + 8 * (r >> 2);
                        lds_f[rl * 256 + col] = acc[mb][nb][r];
                    }
                }
            }
        }
        LGK0; BAR;
        #pragma unroll
        for (int k = 0; k < 8; ++k) {
            const int rl  = k * 8 + w;
            const int row = m0 + c * 64 + rl;
            f32x4 v  = *(const f32x4*)(lds_f + (rl * 64 + l) * 4);
            ushort4 yu = *(const ushort4*)(y0b + (size_t)row * NOUT + n0c + l * 4);
            f32x4 yv;
            yv.x = __builtin_bit_cast(float, (unsigned int)yu.x << 16);
            yv.y = __builtin_bit_cast(float, (unsigned int)yu.y << 16);
            yv.z = __builtin_bit_cast(float, (unsigned int)yu.z << 16);
            yv.w = __builtin_bit_cast(float, (unsigned int)yu.w << 16);
            f32x4 o  = v + yv + bvv;
            __builtin_nontemporal_store(o, (f32x4*)(outp + (size_t)row * NOUT + n0c + l * 4));
        }
        BAR;
    }
}

// ---- zero-scratch correctness fallback (only if ws_size is tiny) ----
__global__ void fused_fallback(const float* __restrict__ x, const float* __restrict__ wmu,
                               const float* __restrict__ wls, const float* __restrict__ r1,
                               const float* __restrict__ bmu, const float* __restrict__ bls,
                               const float* __restrict__ r2, float* __restrict__ out) {
    __shared__ float Xs[16][64];
    __shared__ float Ws[16][64];
    int b0 = blockIdx.x * 16, o0 = blockIdx.y * 16, s = blockIdx.z;
    int tb = threadIdx.x >> 4, to = threadIdx.x & 15;
    float acc = 0.f;
    for (int k0 = 0; k0 < NIN; k0 += 64) {
        __syncthreads();
        #pragma unroll
        for (int j = 0; j < 4; ++j) {
            int e = j * 256 + threadIdx.x;
            int r = e >> 6, cc = e & 63;
            Xs[r][cc] = x[(size_t)(b0 + r) * NIN + k0 + cc];
            size_t wi = (size_t)(o0 + r) * NIN + k0 + cc;
            Ws[r][cc] = wmu[wi] + __expf(wls[wi]) * r1[(size_t)s * NIN * NOUT + wi];
        }
        __syncthreads();
        for (int k = 0; k < 64; ++k) acc += Xs[tb][k] * Ws[to][k];
    }
    int o = o0 + to;
    out[((size_t)s * NB + b0 + tb) * NOUT + o] = acc + bmu[o] + __expf(bls[o]) * r2[s * NOUT + o];
}

extern "C" void kernel_launch(void* const* d_in, const int* in_sizes, int n_in,
                              void* d_out, int out_size, void* d_ws, size_t ws_size,
                              hipStream_t stream) {
    const float* x   = (const float*)d_in[0];
    const float* wmu = (const float*)d_in[1];
    const float* wls = (const float*)d_in[2];
    const float* bmu = (const float*)d_in[3];
    const float* bls = (const float*)d_in[4];
    const float* r1  = (const float*)d_in[5];
    const float* r2  = (const float*)d_in[6];
    const int S = in_sizes[6] / NOUT;
    float* out = (float*)d_out;

    const size_t xb_b   = (size_t)NB * NIN * 2;       // 8 MB  bf16 x
    const size_t xf8_b  = (size_t)NB * NIN;           // 4 MB  fp8 x
    const size_t wmub_b = (size_t)NOUT * NIN * 2;     // 2 MB  bf16 w_mu
    const size_t y0_b   = (size_t)NB * NOUT * 2;      // 8 MB  bf16 y0
    const size_t bias_b = (size_t)S * NOUT * 4;
    const size_t per_s  = (size_t)NOUT * NIN;         // 1 MB fp8 per sample
    const size_t base_b = xb_b + xf8_b + wmub_b + y0_b + bias_b;

    if (ws_size < base_b + per_s) {
        dim3 gg(NB / 16, NOUT / 16, S);
        fused_fallback<<<gg, 256, 0, stream>>>(x, wmu, wls, r1, bmu, bls, r2, out);
        return;
    }

    char* ws = (char*)d_ws;
    unsigned short* xb   = (unsigned short*)ws;
    unsigned char*  xf8  = (unsigned char*)(ws + xb_b);
    unsigned short* wmub = (unsigned short*)(ws + xb_b + xf8_b);
    unsigned short* y0b  = (unsigned short*)(ws + xb_b + xf8_b + wmub_b);
    float*          bias = (float*)(ws + xb_b + xf8_b + wmub_b + y0_b);
    unsigned char*  rf8  = (unsigned char*)(ws + base_b);

    int SC = (int)((ws_size - base_b) / per_s);
    if (SC > S) SC = S;

    cvt_x_both<<<NB * NIN / 1024, 256, 0, stream>>>(x, xb, (unsigned int*)xf8);
    cvt_x_kernel<<<NOUT * NIN / 1024, 256, 0, stream>>>(wmu, wmub);
    bias_kernel<<<(S * NOUT + 255) / 256, 256, 0, stream>>>(bmu, bls, r2, bias, S * NOUT);

    // y0 = x . w_mu^T   (bf16 output, 64 blocks)
    gemm256<<<64, 512, 0, stream>>>(xb, wmub, y0b, 64);

    for (int s0 = 0; s0 < S; s0 += SC) {
        int sc = (S - s0 < SC) ? (S - s0) : SC;
        cvt_r1_fp8<<<sc * (NOUT * NIN / 1024), 256, 0, stream>>>(wls, r1, (unsigned int*)rf8, s0);
        int nwg = 64 * sc;   // 16 mi x 4*sc ni, always % 8 == 0
        gemm256mx<<<nwg, 512, 0, stream>>>(xf8, rf8, y0b, bias, out, s0, nwg);
    }
}